// Round 1
// baseline (1095.240 us; speedup 1.0000x reference)
//
#include <hip/hip_runtime.h>

// Sinkhorn divergence, 512 independent 256-point problems.
// x cloud = obs, y cloud = syn (reference: vmap(_sinkhorn_divergence)(flat_obs, flat_syn)).
//
// Per step (eps), per softmin with rows P / cols Q and col-potential h:
//   softmin_i = 0.5*||P_i||^2 - eps*ln2 * ( m_i + log2( sum_j 2^{ arg2_ij - m_i } ) )
//   arg2_ij   = H2[j] + (t_i*t_j)*inv + (p_i*q_j)*inv ,  inv = log2e/eps
//   H2[j]     = -8 + (h_pot[j] - 0.5*||Q_j||^2) * inv      (la*log2e = -log2 256 = -8)
// t_i*t_j*inv is affine in j -> running accumulator (1 add), no load.
// Thread tid owns row tid of all 4 softmins and supplies column tid data.

constexpr int   N      = 256;   // points per cloud (NT / SPARSE)
constexpr int   NPROB  = 512;   // B*S*NR
constexpr int   NRDIM  = 64;
constexpr float DT_F   = 0.001f;
constexpr float EPS_MIN = 1e-4f;   // BLUR^P
constexpr int   NSTEPS = 24;
constexpr float LOG2E  = 1.4426950408889634f;
constexpr float LN2    = 0.6931471805599453f;

extern "C" __global__ void __launch_bounds__(256, 2)
sinkhorn_div_kernel(const float* __restrict__ syn,
                    const float* __restrict__ obs,
                    float* __restrict__ divs)
{
    const int p   = blockIdx.x;          // ((b*S + s)*NR + r)
    const int r   = p & (NRDIM - 1);
    const int bs  = p >> 6;              // b*S + s
    const int tid = threadIdx.x;         // row index i, also column index j=tid

    __shared__ float4 ya[N];             // (Hxy, Hyy, y_j*inv, 0)  y-columns
    __shared__ float4 xa[N];             // (Hyx, Hxx, x_j*inv, 0)  x-columns
    __shared__ float  red[16];

    // ---- load this thread's point values (strided gather, tiny traffic) ----
    const size_t base = (size_t)bs * N * NRDIM + r;
    const float xi = obs[base + (size_t)tid * NRDIM];   // x cloud = obs
    const float yi = syn[base + (size_t)tid * NRDIM];   // y cloud = syn

    // ---- block reductions: value max/min (diameter), sum|obs|, sum|syn| (mask) ----
    float hi = fmaxf(xi, yi), lo = fminf(xi, yi);
    float ax = fabsf(xi),     ay = fabsf(yi);
    #pragma unroll
    for (int off = 32; off > 0; off >>= 1) {
        hi  = fmaxf(hi, __shfl_down(hi, off, 64));
        lo  = fminf(lo, __shfl_down(lo, off, 64));
        ax += __shfl_down(ax, off, 64);
        ay += __shfl_down(ay, off, 64);
    }
    const int wave = tid >> 6;
    if ((tid & 63) == 0) {
        red[wave * 4 + 0] = hi;  red[wave * 4 + 1] = lo;
        red[wave * 4 + 2] = ax;  red[wave * 4 + 3] = ay;
    }
    __syncthreads();
    const float vmax = fmaxf(fmaxf(red[0], red[4]), fmaxf(red[8],  red[12]));
    const float vmin = fminf(fminf(red[1], red[5]), fminf(red[9],  red[13]));
    const float sax  = red[2] + red[6] + red[10] + red[14];
    const float say  = red[3] + red[7] + red[11] + red[15];

    const float tspread  = 255.0f * DT_F;                 // t-dim spread (both clouds)
    const float diameter = fmaxf(tspread, vmax - vmin);
    float eps_raw = diameter * diameter;                  // eps0 = diameter^P, P=2

    const float ti    = (float)tid * DT_F;
    const float selfx = 0.5f * (ti * ti + xi * xi);       // 0.5*||P_i||^2, x cloud
    const float selfy = 0.5f * (ti * ti + yi * yi);       // y cloud

    float f = 0.0f, g = 0.0f, px = 0.0f, py = 0.0f;

    for (int step = 0; step < NSTEPS; ++step) {
        const float eps = fmaxf(eps_raw, EPS_MIN);
        const float inv = LOG2E / eps;

        // ---- prologue: this thread provides column j = tid of all arrays ----
        {
            const float la2 = -8.0f;   // log2(1/256)
            const float Hxy = fmaf(g  - selfy, inv, la2);   // cols=y, pot=g
            const float Hyy = fmaf(py - selfy, inv, la2);   // cols=y, pot=py
            const float Hyx = fmaf(f  - selfx, inv, la2);   // cols=x, pot=f
            const float Hxx = fmaf(px - selfx, inv, la2);   // cols=x, pot=px
            ya[tid] = make_float4(Hxy, Hyy, yi * inv, 0.0f);
            xa[tid] = make_float4(Hyx, Hxx, xi * inv, 0.0f);
        }
        __syncthreads();

        const float a = ti * DT_F * inv;    // increment of t_i*t_j*inv per j

        // ---- pass 1: exact row maxima of the 4 arg matrices ----
        float m0 = -3.4e38f, m1 = -3.4e38f, m2 = -3.4e38f, m3 = -3.4e38f;
        float rr = 0.0f;
        #pragma unroll 4
        for (int j = 0; j < N; ++j) {
            const float4 yA = ya[j];
            const float4 xA = xa[j];
            m0 = fmaxf(m0, fmaf(xi, yA.z, yA.x + rr));   // xy: row x, col y
            m3 = fmaxf(m3, fmaf(yi, yA.z, yA.y + rr));   // yy: row y, col y
            m1 = fmaxf(m1, fmaf(yi, xA.z, xA.x + rr));   // yx: row y, col x
            m2 = fmaxf(m2, fmaf(xi, xA.z, xA.y + rr));   // xx: row x, col x
            rr += a;
        }

        // ---- pass 2: shifted sums (fold -m into the running t-term) ----
        float s0 = 0.0f, s1 = 0.0f, s2 = 0.0f, s3 = 0.0f;
        float r0 = -m0, r1 = -m1, r2 = -m2, r3 = -m3;
        #pragma unroll 4
        for (int j = 0; j < N; ++j) {
            const float4 yA = ya[j];
            const float4 xA = xa[j];
            s0 += __builtin_amdgcn_exp2f(fmaf(xi, yA.z, yA.x + r0));
            s3 += __builtin_amdgcn_exp2f(fmaf(yi, yA.z, yA.y + r3));
            s1 += __builtin_amdgcn_exp2f(fmaf(yi, xA.z, xA.x + r1));
            s2 += __builtin_amdgcn_exp2f(fmaf(xi, xA.z, xA.y + r2));
            r0 += a; r1 += a; r2 += a; r3 += a;
        }

        const float el2 = eps * LN2;
        const float fn  = selfx - el2 * (m0 + __builtin_amdgcn_logf(s0));
        const float gn  = selfy - el2 * (m1 + __builtin_amdgcn_logf(s1));
        const float pxn = 0.5f * (px + (selfx - el2 * (m2 + __builtin_amdgcn_logf(s2))));
        const float pyn = 0.5f * (py + (selfy - el2 * (m3 + __builtin_amdgcn_logf(s3))));
        f = fn; g = gn; px = pxn; py = pyn;

        eps_raw *= 0.25f;
        __syncthreads();   // protect ya/xa before next prologue overwrites
    }

    // ---- divergence: (1/n) * sum_i [(f_i - px_i) + (g_i - py_i)] ----
    float contrib = (f - px) + (g - py);
    #pragma unroll
    for (int off = 32; off > 0; off >>= 1)
        contrib += __shfl_down(contrib, off, 64);
    if ((tid & 63) == 0) red[wave] = contrib;
    __syncthreads();
    if (tid == 0) {
        const float total = (red[0] + red[1] + red[2] + red[3]) * (1.0f / (float)N);
        const bool masked_out = (sax == 0.0f) && (say == 0.0f);  // drop only if BOTH all-zero
        divs[p] = masked_out ? 0.0f : total;
    }
}

extern "C" __global__ void __launch_bounds__(256)
reduce_out_kernel(const float* __restrict__ divs, float* __restrict__ out)
{
    const int b   = blockIdx.x;       // output batch index
    const int tid = threadIdx.x;
    __shared__ float red[4];
    float v = divs[b * 256 + tid];    // 256 = S*NR problems per batch
    #pragma unroll
    for (int off = 32; off > 0; off >>= 1)
        v += __shfl_down(v, off, 64);
    if ((tid & 63) == 0) red[tid >> 6] = v;
    __syncthreads();
    if (tid == 0) out[b] = red[0] + red[1] + red[2] + red[3];
}

extern "C" void kernel_launch(void* const* d_in, const int* in_sizes, int n_in,
                              void* d_out, int out_size, void* d_ws, size_t ws_size,
                              hipStream_t stream) {
    const float* syn = (const float*)d_in[0];   // syn_data
    const float* obs = (const float*)d_in[1];   // obs_data
    float* divs = (float*)d_ws;                 // 512 floats scratch

    sinkhorn_div_kernel<<<NPROB, 256, 0, stream>>>(syn, obs, divs);
    reduce_out_kernel<<<2, 256, 0, stream>>>(divs, (float*)d_out);
}

// Round 2
// 874.602 us; speedup vs baseline: 1.2523x; 1.2523x over previous
//
#include <hip/hip_runtime.h>

// Sinkhorn divergence, 512 independent 256-point problems, 24 annealing steps.
// Round 2: 1024-thread blocks — each problem's columns split across 4
// quarters (q = tid>>8), rows duplicated per quarter. Cross-quarter
// (max, sum) combine via LDS each step; potentials recomputed identically
// in every quarter (bit-deterministic). 512 blocks x 16 waves = 32 waves/CU.
//
// Math (log2 domain, per softmin with rows P / cols Q, col-potential h):
//   softmin_i = 0.5||P_i||^2 - eps*ln2*( m_i + log2 sum_j 2^{arg_ij - m_i} )
//   arg_ij    = H2[j] + t_i*t_j*inv + p_i*q_j*inv ,  inv = log2e/eps
//   H2[j]     = -8 + (h[j] - 0.5||Q_j||^2)*inv        (la*log2e = -log2 256)
// t_i*t_j*inv is affine in j -> running accumulator.

constexpr int   N       = 256;   // points per cloud
constexpr int   NPROB   = 512;   // B*S*NR
constexpr int   NRDIM   = 64;
constexpr float DT_F    = 0.001f;
constexpr float EPS_MIN = 1e-4f; // BLUR^P
constexpr int   NSTEPS  = 24;
constexpr float LOG2E   = 1.4426950408889634f;
constexpr float LN2     = 0.6931471805599453f;
constexpr int   NT      = 1024;  // threads per block
constexpr int   CPQ     = 64;    // columns per quarter

extern "C" __global__ void __launch_bounds__(NT, 8)
sinkhorn_div_kernel(const float* __restrict__ syn,
                    const float* __restrict__ obs,
                    float* __restrict__ divs)
{
    const int p   = blockIdx.x;          // ((b*S + s)*NR + r)
    const int r   = p & (NRDIM - 1);
    const int bs  = p >> 6;
    const int tid = threadIdx.x;
    const int row = tid & (N - 1);       // row index i (duplicated x4)
    const int q   = tid >> 8;            // column quarter 0..3

    __shared__ float4 ya[N];             // (Hxy, Hyy, y_j*inv, 0)
    __shared__ float4 xa[N];             // (Hyx, Hxx, x_j*inv, 0)
    __shared__ float4 msh[NT];           // per-thread partial maxima
    __shared__ float4 ssh[NT];           // per-thread partial sums
    __shared__ float  redA[64];

    const size_t base = (size_t)bs * N * NRDIM + r;
    const float xi = obs[base + (size_t)row * NRDIM];   // x cloud = obs
    const float yi = syn[base + (size_t)row * NRDIM];   // y cloud = syn

    // ---- block reductions: diameter (max/min) + all-zero mask sums ----
    float hi = fmaxf(xi, yi), lo = fminf(xi, yi);
    float ax = fabsf(xi),     ay = fabsf(yi);
    #pragma unroll
    for (int off = 32; off > 0; off >>= 1) {
        hi  = fmaxf(hi, __shfl_down(hi, off, 64));
        lo  = fminf(lo, __shfl_down(lo, off, 64));
        ax += __shfl_down(ax, off, 64);
        ay += __shfl_down(ay, off, 64);
    }
    const int wave = tid >> 6;           // 0..15
    if ((tid & 63) == 0) {
        redA[wave * 4 + 0] = hi;  redA[wave * 4 + 1] = lo;
        redA[wave * 4 + 2] = ax;  redA[wave * 4 + 3] = ay;
    }
    __syncthreads();
    float vmax = -3.4e38f, vmin = 3.4e38f, sax = 0.0f, say = 0.0f;
    #pragma unroll
    for (int w = 0; w < 16; ++w) {
        vmax = fmaxf(vmax, redA[w * 4 + 0]);
        vmin = fminf(vmin, redA[w * 4 + 1]);
        sax += redA[w * 4 + 2];
        say += redA[w * 4 + 3];
    }

    const float tspread  = 255.0f * DT_F;
    const float diameter = fmaxf(tspread, vmax - vmin);
    float eps_raw = diameter * diameter;              // eps0 = diameter^2

    const float ti    = (float)row * DT_F;
    const float selfx = 0.5f * (ti * ti + xi * xi);
    const float selfy = 0.5f * (ti * ti + yi * yi);

    float f = 0.0f, g = 0.0f, px = 0.0f, py = 0.0f;

    const int j0 = q * CPQ;

    for (int step = 0; step < NSTEPS; ++step) {
        const float eps = fmaxf(eps_raw, EPS_MIN);
        const float inv = LOG2E / eps;

        // ---- prologue: quarter 0 provides column j = row of all arrays ----
        if (q == 0) {
            const float la2 = -8.0f;   // log2(1/256)
            const float Hxy = fmaf(g  - selfy, inv, la2);
            const float Hyy = fmaf(py - selfy, inv, la2);
            const float Hyx = fmaf(f  - selfx, inv, la2);
            const float Hxx = fmaf(px - selfx, inv, la2);
            ya[row] = make_float4(Hxy, Hyy, yi * inv, 0.0f);
            xa[row] = make_float4(Hyx, Hxx, xi * inv, 0.0f);
        }
        __syncthreads();   // S1

        const float a = ti * DT_F * inv;      // t-term increment per j

        // ---- pass 1: partial row maxima over this quarter's columns ----
        float m0 = -3.4e38f, m1 = -3.4e38f, m2 = -3.4e38f, m3 = -3.4e38f;
        float rr = a * (float)j0;
        #pragma unroll 4
        for (int j = j0; j < j0 + CPQ; ++j) {
            const float4 yA = ya[j];
            const float4 xA = xa[j];
            m0 = fmaxf(m0, fmaf(xi, yA.z, yA.x + rr));   // xy
            m3 = fmaxf(m3, fmaf(yi, yA.z, yA.y + rr));   // yy
            m1 = fmaxf(m1, fmaf(yi, xA.z, xA.x + rr));   // yx
            m2 = fmaxf(m2, fmaf(xi, xA.z, xA.y + rr));   // xx
            rr += a;
        }
        msh[tid] = make_float4(m0, m1, m2, m3);
        __syncthreads();   // S2

        // ---- combine maxima across the 4 quarters (identical in all) ----
        {
            const float4 ma = msh[row];
            const float4 mb = msh[row + 256];
            const float4 mc = msh[row + 512];
            const float4 md = msh[row + 768];
            m0 = fmaxf(fmaxf(ma.x, mb.x), fmaxf(mc.x, md.x));
            m1 = fmaxf(fmaxf(ma.y, mb.y), fmaxf(mc.y, md.y));
            m2 = fmaxf(fmaxf(ma.z, mb.z), fmaxf(mc.z, md.z));
            m3 = fmaxf(fmaxf(ma.w, mb.w), fmaxf(mc.w, md.w));
        }

        // ---- pass 2: partial shifted sums over this quarter's columns ----
        float s0 = 0.0f, s1 = 0.0f, s2 = 0.0f, s3 = 0.0f;
        {
            const float rbase = a * (float)j0;
            float r0 = rbase - m0, r1 = rbase - m1, r2 = rbase - m2, r3 = rbase - m3;
            #pragma unroll 4
            for (int j = j0; j < j0 + CPQ; ++j) {
                const float4 yA = ya[j];
                const float4 xA = xa[j];
                s0 += __builtin_amdgcn_exp2f(fmaf(xi, yA.z, yA.x + r0));
                s3 += __builtin_amdgcn_exp2f(fmaf(yi, yA.z, yA.y + r3));
                s1 += __builtin_amdgcn_exp2f(fmaf(yi, xA.z, xA.x + r1));
                s2 += __builtin_amdgcn_exp2f(fmaf(xi, xA.z, xA.y + r2));
                r0 += a; r1 += a; r2 += a; r3 += a;
            }
        }
        ssh[tid] = make_float4(s0, s1, s2, s3);
        __syncthreads();   // S3

        // ---- combine sums across quarters (fixed order -> deterministic) ----
        {
            const float4 sa = ssh[row];
            const float4 sb = ssh[row + 256];
            const float4 sc = ssh[row + 512];
            const float4 sd = ssh[row + 768];
            s0 = (sa.x + sb.x) + (sc.x + sd.x);
            s1 = (sa.y + sb.y) + (sc.y + sd.y);
            s2 = (sa.z + sb.z) + (sc.z + sd.z);
            s3 = (sa.w + sb.w) + (sc.w + sd.w);
        }

        // ---- epilogue: every quarter computes identical new potentials ----
        const float el2 = eps * LN2;
        const float fn  = selfx - el2 * (m0 + __builtin_amdgcn_logf(s0));
        const float gn  = selfy - el2 * (m1 + __builtin_amdgcn_logf(s1));
        const float pxn = 0.5f * (px + (selfx - el2 * (m2 + __builtin_amdgcn_logf(s2))));
        const float pyn = 0.5f * (py + (selfy - el2 * (m3 + __builtin_amdgcn_logf(s3))));
        f = fn; g = gn; px = pxn; py = pyn;

        eps_raw *= 0.25f;
        // no barrier here: S1 of the next step separates the prologue write
        // (after this point) from this step's pass-2 reads (before S3).
    }

    // ---- divergence: (1/n) * sum_i [(f-px)+(g-py)], rows duplicated x4 ----
    float contrib = (f - px) + (g - py);
    #pragma unroll
    for (int off = 32; off > 0; off >>= 1)
        contrib += __shfl_down(contrib, off, 64);
    __syncthreads();                      // redA reuse
    if ((tid & 63) == 0) redA[wave] = contrib;
    __syncthreads();
    if (tid == 0) {
        float total = 0.0f;
        #pragma unroll
        for (int w = 0; w < 16; ++w) total += redA[w];
        total *= (1.0f / (float)(4 * N));             // x4 duplication
        const bool masked_out = (sax == 0.0f) && (say == 0.0f);
        divs[p] = masked_out ? 0.0f : total;
    }
}

extern "C" __global__ void __launch_bounds__(256)
reduce_out_kernel(const float* __restrict__ divs, float* __restrict__ out)
{
    const int b   = blockIdx.x;
    const int tid = threadIdx.x;
    __shared__ float red[4];
    float v = divs[b * 256 + tid];        // 256 = S*NR problems per batch
    #pragma unroll
    for (int off = 32; off > 0; off >>= 1)
        v += __shfl_down(v, off, 64);
    if ((tid & 63) == 0) red[tid >> 6] = v;
    __syncthreads();
    if (tid == 0) out[b] = red[0] + red[1] + red[2] + red[3];
}

extern "C" void kernel_launch(void* const* d_in, const int* in_sizes, int n_in,
                              void* d_out, int out_size, void* d_ws, size_t ws_size,
                              hipStream_t stream) {
    const float* syn = (const float*)d_in[0];   // syn_data
    const float* obs = (const float*)d_in[1];   // obs_data
    float* divs = (float*)d_ws;                 // 512 floats scratch

    sinkhorn_div_kernel<<<NPROB, NT, 0, stream>>>(syn, obs, divs);
    reduce_out_kernel<<<2, 256, 0, stream>>>(divs, (float*)d_out);
}